// Round 1
// baseline (3497.062 us; speedup 1.0000x reference)
//
#include <hip/hip_runtime.h>
#include <math.h>

#define NN 6144
#define DSZ 2048
#define TSZ 4096
#define NE 1048576
#define NE_TOT (NE + NN)
#define NEG_SLOPE 0.2f
#define GGAMMA 0.03125f

// ---------------- CSR build (counting sort by dst) ----------------
__global__ void hist_kernel(const int* __restrict__ ei, int* __restrict__ cnt) {
    int e = blockIdx.x * blockDim.x + threadIdx.x;
    if (e >= NE_TOT) return;
    int d = (e < NE) ? ei[NE + e] : (e - NE);
    atomicAdd(&cnt[d], 1);
}

__global__ void scan_kernel(const int* __restrict__ cnt, int* __restrict__ row_ofs) {
    // single block, 1024 threads, 6 elements each (6144 total)
    __shared__ int part[1024];
    int t = threadIdx.x;
    int local[6];
    int s = 0;
#pragma unroll
    for (int i = 0; i < 6; i++) { local[i] = s; s += cnt[t * 6 + i]; }
    part[t] = s;
    __syncthreads();
    for (int off = 1; off < 1024; off <<= 1) {
        int v = (t >= off) ? part[t - off] : 0;
        __syncthreads();
        part[t] += v;
        __syncthreads();
    }
    int base = (t == 0) ? 0 : part[t - 1];
#pragma unroll
    for (int i = 0; i < 6; i++) row_ofs[t * 6 + i] = base + local[i];
    if (t == 1023) row_ofs[NN] = part[1023];
}

__global__ void copy_cursor(const int* __restrict__ row_ofs, int* __restrict__ cursor) {
    int i = blockIdx.x * blockDim.x + threadIdx.x;
    if (i < NN) cursor[i] = row_ofs[i];
}

__global__ void scatter_kernel(const int* __restrict__ ei, int* __restrict__ cursor,
                               int* __restrict__ col) {
    int e = blockIdx.x * blockDim.x + threadIdx.x;
    if (e >= NE_TOT) return;
    int s, d;
    if (e < NE) { s = ei[e]; d = ei[NE + e]; } else { s = e - NE; d = s; }
    int pos = atomicAdd(&cursor[d], 1);
    col[pos] = s;
}

// ---------------- generic fp32 GEMM: C[M,N] = A[M,K] @ B[K,N] ----------------
// 64x64 tile, BK=16, 256 threads, 4x4 per thread. ATOMIC variant: split-K over gridDim.z.
template <bool ATOMIC>
__global__ __launch_bounds__(256) void gemm64(const float* __restrict__ A,
                                              const float* __restrict__ B,
                                              float* __restrict__ C,
                                              int M, int N, int K) {
    __shared__ float As[16][68];
    __shared__ float Bs[16][68];
    const int tid = threadIdx.x;
    const int tn = tid & 15, tm = tid >> 4;
    const int bm = blockIdx.y * 64, bn = blockIdx.x * 64;
    const int ar = tid >> 2, ac = (tid & 3) * 4;
    const int br = tid >> 4, bc = (tid & 15) * 4;
    int kbeg = 0, kend = K;
    if constexpr (ATOMIC) {
        int klen = K / gridDim.z;
        kbeg = blockIdx.z * klen;
        kend = kbeg + klen;
    }
    const float* Ap = A + (size_t)(bm + ar) * K + ac;
    const float* Bp = B + (size_t)br * N + bn + bc;
    float acc[4][4] = {};
    for (int k0 = kbeg; k0 < kend; k0 += 16) {
        float4 av = *(const float4*)(Ap + k0);
        float4 bv = *(const float4*)(Bp + (size_t)k0 * N);
        As[ac + 0][ar] = av.x; As[ac + 1][ar] = av.y;
        As[ac + 2][ar] = av.z; As[ac + 3][ar] = av.w;
        *(float4*)&Bs[br][bc] = bv;
        __syncthreads();
#pragma unroll
        for (int k = 0; k < 16; k++) {
            float4 a4 = *(const float4*)&As[k][tm * 4];
            float4 b4 = *(const float4*)&Bs[k][tn * 4];
            float aa[4] = {a4.x, a4.y, a4.z, a4.w};
            float bb[4] = {b4.x, b4.y, b4.z, b4.w};
#pragma unroll
            for (int i = 0; i < 4; i++)
#pragma unroll
                for (int j = 0; j < 4; j++) acc[i][j] = fmaf(aa[i], bb[j], acc[i][j]);
        }
        __syncthreads();
    }
#pragma unroll
    for (int i = 0; i < 4; i++) {
        float* cp = C + (size_t)(bm + tm * 4 + i) * N + bn + tn * 4;
        if constexpr (ATOMIC) {
#pragma unroll
            for (int j = 0; j < 4; j++) atomicAdd(cp + j, acc[i][j]);
        } else {
            *(float4*)cp = make_float4(acc[i][0], acc[i][1], acc[i][2], acc[i][3]);
        }
    }
}

// ---------------- per-node attention scalars ----------------
// s_src[n,h] = z[n,h,:].a_src[h]; s_dst[n,h] = z[n,h,:].a_dst[h]
__global__ void attn_scores(const float* __restrict__ z, const float* __restrict__ a_src,
                            const float* __restrict__ a_dst, float* __restrict__ s_src,
                            float* __restrict__ s_dst, int Fout, int F) {
    int n = blockIdx.x, t = threadIdx.x;
    __shared__ float r1[256], r2[256];
    float v = (t < Fout) ? z[(size_t)n * Fout + t] : 0.f;
    r1[t] = (t < Fout) ? v * a_src[t] : 0.f;
    r2[t] = (t < Fout) ? v * a_dst[t] : 0.f;
    __syncthreads();
    for (int off = F >> 1; off > 0; off >>= 1) {
        if ((t & (F - 1)) < off) { r1[t] += r1[t + off]; r2[t] += r2[t + off]; }
        __syncthreads();
    }
    if (t < Fout && (t & (F - 1)) == 0) {
        int h = t / F;
        s_src[n * 4 + h] = r1[t];
        s_dst[n * 4 + h] = r2[t];
    }
}

// ---------------- GAT aggregate: segment softmax + weighted scatter + bias + relu ----------------
// one wave (64 lanes) per destination node; each lane owns FOUT/64 consecutive features
template <int FOUT, int F>
__global__ __launch_bounds__(256) void gat_aggregate(
    const float* __restrict__ z, const int* __restrict__ row_ofs,
    const int* __restrict__ col, const float* __restrict__ s_src,
    const float* __restrict__ s_dst, const float* __restrict__ bias,
    float* __restrict__ H) {
    constexpr int VPL = FOUT / 64;
    int wave = threadIdx.x >> 6, lane = threadIdx.x & 63;
    int n = blockIdx.x * 4 + wave;
    int beg = row_ofs[n], end = row_ofs[n + 1];
    int f0 = lane * VPL;
    int h = f0 / F;  // 16-lane head groups for both FOUT=256 and 128
    float4 sd4 = *(const float4*)&s_dst[n * 4];
    // pass 1: per-head max of leaky_relu(logit) over this node's incoming edges
    float mx[4] = {-__builtin_inff(), -__builtin_inff(), -__builtin_inff(), -__builtin_inff()};
    for (int e = beg + lane; e < end; e += 64) {
        int s = col[e];
        float4 ss = *(const float4*)&s_src[s * 4];
        float l0 = ss.x + sd4.x; l0 = l0 > 0.f ? l0 : NEG_SLOPE * l0;
        float l1 = ss.y + sd4.y; l1 = l1 > 0.f ? l1 : NEG_SLOPE * l1;
        float l2 = ss.z + sd4.z; l2 = l2 > 0.f ? l2 : NEG_SLOPE * l2;
        float l3 = ss.w + sd4.w; l3 = l3 > 0.f ? l3 : NEG_SLOPE * l3;
        mx[0] = fmaxf(mx[0], l0); mx[1] = fmaxf(mx[1], l1);
        mx[2] = fmaxf(mx[2], l2); mx[3] = fmaxf(mx[3], l3);
    }
#pragma unroll
    for (int off = 32; off > 0; off >>= 1) {
#pragma unroll
        for (int hh = 0; hh < 4; hh++) mx[hh] = fmaxf(mx[hh], __shfl_xor(mx[hh], off));
    }
    float mh = (h == 0) ? mx[0] : (h == 1) ? mx[1] : (h == 2) ? mx[2] : mx[3];
    float sdh = (h == 0) ? sd4.x : (h == 1) ? sd4.y : (h == 2) ? sd4.z : sd4.w;
    // pass 2: accumulate exp(l - m) * z[src, myfeats]
    float acc[VPL] = {};
    float wsum = 0.f;
    for (int e = beg; e < end; e++) {
        int s = col[e];
        float l = s_src[s * 4 + h] + sdh;
        l = l > 0.f ? l : NEG_SLOPE * l;
        float w = expf(l - mh);
        wsum += w;
        const float* zp = z + (size_t)s * FOUT + f0;
        if constexpr (VPL == 4) {
            float4 zv = *(const float4*)zp;
            acc[0] = fmaf(w, zv.x, acc[0]); acc[1] = fmaf(w, zv.y, acc[1]);
            acc[2] = fmaf(w, zv.z, acc[2]); acc[3] = fmaf(w, zv.w, acc[3]);
        } else {
            float2 zv = *(const float2*)zp;
            acc[0] = fmaf(w, zv.x, acc[0]); acc[1] = fmaf(w, zv.y, acc[1]);
        }
    }
    float inv = 1.f / wsum;
#pragma unroll
    for (int i = 0; i < VPL; i++) {
        float o = acc[i] * inv + bias[f0 + i];
        H[(size_t)n * FOUT + f0 + i] = o > 0.f ? o : 0.f;
    }
}

// ---------------- GIP: row min-max normalize + row sq-norm ----------------
__global__ void gip_norm(const float* __restrict__ Y, float* __restrict__ Yn,
                         float* __restrict__ r, int Fout) {
    int row = blockIdx.x, t = threadIdx.x;  // blockDim.x == Fout
    __shared__ float s1[256], s2[256];
    float v = Y[(size_t)row * Fout + t];
    s1[t] = v; s2[t] = v;
    __syncthreads();
    for (int off = blockDim.x >> 1; off > 0; off >>= 1) {
        if (t < off) {
            s1[t] = fminf(s1[t], s1[t + off]);
            s2[t] = fmaxf(s2[t], s2[t + off]);
        }
        __syncthreads();
    }
    float mn = s1[0], mx = s2[0];
    float rng = mx - mn;
    if (rng == 0.f) rng = 1.f;
    float yn = (v - mn) / rng;
    Yn[(size_t)row * Fout + t] = yn;
    __syncthreads();
    s1[t] = yn * yn;
    __syncthreads();
    for (int off = blockDim.x >> 1; off > 0; off >>= 1) {
        if (t < off) s1[t] += s1[t + off];
        __syncthreads();
    }
    if (t == 0) r[row] = s1[0];
}

__global__ void mean_reduce(const float* __restrict__ r, float* __restrict__ md0, int M) {
    __shared__ float s[1024];
    int t = threadIdx.x;
    float acc = 0.f;
    for (int i = t; i < M; i += 1024) acc += r[i];
    s[t] = acc;
    __syncthreads();
    for (int off = 512; off > 0; off >>= 1) {
        if (t < off) s[t] += s[t + off];
        __syncthreads();
    }
    if (t == 0) md0[0] = s[0] / (float)M;
}

// ---------------- gram GEMM (A@A^T) with fused GIP epilogue: Kacc += p*exp(-g*(ri+rj-2G)/md0)
__global__ __launch_bounds__(256) void gram64(const float* __restrict__ Y,
                                              float* __restrict__ Kacc,
                                              const float* __restrict__ rbuf,
                                              const float* __restrict__ md0buf,
                                              float p, int M, int K) {
    __shared__ float As[16][68];
    __shared__ float Bs[16][68];
    const int tid = threadIdx.x;
    const int tn = tid & 15, tm = tid >> 4;
    const int bm = blockIdx.y * 64, bn = blockIdx.x * 64;
    const int ar = tid >> 2, ac = (tid & 3) * 4;
    const float* Ap = Y + (size_t)(bm + ar) * K + ac;
    const float* Bp = Y + (size_t)(bn + ar) * K + ac;
    float acc[4][4] = {};
    for (int k0 = 0; k0 < K; k0 += 16) {
        float4 av = *(const float4*)(Ap + k0);
        float4 bv = *(const float4*)(Bp + k0);
        As[ac + 0][ar] = av.x; As[ac + 1][ar] = av.y;
        As[ac + 2][ar] = av.z; As[ac + 3][ar] = av.w;
        Bs[ac + 0][ar] = bv.x; Bs[ac + 1][ar] = bv.y;
        Bs[ac + 2][ar] = bv.z; Bs[ac + 3][ar] = bv.w;
        __syncthreads();
#pragma unroll
        for (int k = 0; k < 16; k++) {
            float4 a4 = *(const float4*)&As[k][tm * 4];
            float4 b4 = *(const float4*)&Bs[k][tn * 4];
            float aa[4] = {a4.x, a4.y, a4.z, a4.w};
            float bb[4] = {b4.x, b4.y, b4.z, b4.w};
#pragma unroll
            for (int i = 0; i < 4; i++)
#pragma unroll
                for (int j = 0; j < 4; j++) acc[i][j] = fmaf(aa[i], bb[j], acc[i][j]);
        }
        __syncthreads();
    }
    float sc = GGAMMA / md0buf[0];
    float ri[4], rj[4];
#pragma unroll
    for (int i = 0; i < 4; i++) ri[i] = rbuf[bm + tm * 4 + i];
#pragma unroll
    for (int j = 0; j < 4; j++) rj[j] = rbuf[bn + tn * 4 + j];
#pragma unroll
    for (int i = 0; i < 4; i++) {
#pragma unroll
        for (int j = 0; j < 4; j++) {
            float val = p * expf(-(ri[i] + rj[j] - 2.f * acc[i][j]) * sc);
            size_t idx = (size_t)(bm + tm * 4 + i) * M + bn + tn * 4 + j;
            Kacc[idx] += val;
        }
    }
}

// ---------------- misc elementwise ----------------
__global__ void scale_copy(const float* __restrict__ src, float* __restrict__ dst,
                           float p, size_t n) {
    for (size_t i = (size_t)blockIdx.x * blockDim.x + threadIdx.x; i < n;
         i += (size_t)gridDim.x * blockDim.x)
        dst[i] = p * src[i];
}

__global__ void init_min(unsigned* minb) {
    if (threadIdx.x == 0 && blockIdx.x == 0) { minb[0] = 0x7f800000u; minb[1] = 0x7f800000u; }
}

__global__ void min_nonzero(const float* __restrict__ Km, unsigned* __restrict__ minb,
                            size_t total) {
    unsigned lm = 0x7f800000u;
    for (size_t i = (size_t)blockIdx.x * blockDim.x + threadIdx.x; i < total;
         i += (size_t)gridDim.x * blockDim.x) {
        float v = fabsf(Km[i]);
        if (v != 0.f) lm = min(lm, __float_as_uint(v));
    }
#pragma unroll
    for (int off = 32; off > 0; off >>= 1)
        lm = min(lm, (unsigned)__shfl_xor((int)lm, off));
    if ((threadIdx.x & 63) == 0) atomicMin(minb, lm);
}

__global__ void diag_abs(const float* __restrict__ Km, float* __restrict__ dbuf, int M) {
    int i = blockIdx.x * blockDim.x + threadIdx.x;
    if (i < M) dbuf[i] = fabsf(Km[(size_t)i * M + i]);
}

__global__ void normdiv(float* __restrict__ Km, const float* __restrict__ dbuf,
                        const unsigned* __restrict__ minb, int M) {
    int colc = blockIdx.x * blockDim.x + threadIdx.x;
    int row = blockIdx.y;
    float minv = __uint_as_float(minb[0]);
    float v = fabsf(Km[(size_t)row * M + colc]);
    if (v == 0.f) v = minv;
    float dj = dbuf[colc];
    if (dj == 0.f) dj = minv;
    Km[(size_t)row * M + colc] = v / dj;
}

// out[i,j] = 0.5*(out[i,j] + Bm[j,i]);  out: [DSZ][TSZ], Bm: [TSZ][DSZ]
__global__ void combine(float* __restrict__ out, const float* __restrict__ Bm) {
    __shared__ float t[32][33];
    int bx = blockIdx.x * 32;  // out col block (j)
    int by = blockIdx.y * 32;  // out row block (i)
    int tx = threadIdx.x & 31, ty = threadIdx.x >> 5;  // 32x8
#pragma unroll
    for (int k = 0; k < 32; k += 8)
        t[ty + k][tx] = Bm[(size_t)(bx + ty + k) * DSZ + by + tx];
    __syncthreads();
#pragma unroll
    for (int k = 0; k < 32; k += 8) {
        size_t idx = (size_t)(by + ty + k) * TSZ + bx + tx;
        out[idx] = 0.5f * (out[idx] + t[tx][ty + k]);
    }
}

// ============================================================================
extern "C" void kernel_launch(void* const* d_in, const int* in_sizes, int n_in,
                              void* d_out, int out_size, void* d_ws, size_t ws_size,
                              hipStream_t stream) {
    (void)in_sizes; (void)n_in; (void)out_size; (void)ws_size;
    const float* x      = (const float*)d_in[0];
    const int*   ei     = (const int*)d_in[1];
    const float* W1     = (const float*)d_in[2];
    const float* as1    = (const float*)d_in[3];
    const float* ad1    = (const float*)d_in[4];
    const float* b1     = (const float*)d_in[5];
    const float* W2     = (const float*)d_in[6];
    const float* as2    = (const float*)d_in[7];
    const float* ad2    = (const float*)d_in[8];
    const float* b2     = (const float*)d_in[9];
    const float* W3     = (const float*)d_in[10];
    const float* as3    = (const float*)d_in[11];
    const float* ad3    = (const float*)d_in[12];
    const float* b3     = (const float*)d_in[13];
    const float* W4     = (const float*)d_in[14];
    const float* as4    = (const float*)d_in[15];
    const float* ad4    = (const float*)d_in[16];
    const float* b4     = (const float*)d_in[17];
    const float* alpha1 = (const float*)d_in[18];
    const float* alpha2 = (const float*)d_in[19];
    const float* dsim   = (const float*)d_in[20];
    const float* tsim   = (const float*)d_in[21];
    float* out = (float*)d_out;

    // ---- workspace carve (region A is aliased by Bmat after graph/H are dead) ----
    char* base = (char*)d_ws;
    size_t off = 0;
    auto carve = [&](size_t bytes) -> void* {
        void* p = base + off;
        off = (off + bytes + 255) & ~(size_t)255;
        return p;
    };
    float* Bmat  = (float*)base;  // [TSZ][DSZ] — aliases region A (dead by then)
    int* col     = (int*)carve((size_t)NE_TOT * 4);
    int* cnt     = (int*)carve((NN + 1) * 4);
    int* row_ofs = (int*)carve((NN + 1) * 4);
    int* cursor  = (int*)carve(NN * 4);
    float* s_src = (float*)carve((size_t)NN * 4 * 4);
    float* s_dst = (float*)carve((size_t)NN * 4 * 4);
    float* z     = (float*)carve((size_t)NN * 256 * 4);
    float* H1    = (float*)carve((size_t)NN * 256 * 4);
    float* H2    = (float*)carve((size_t)NN * 256 * 4);
    float* H3    = (float*)carve((size_t)NN * 256 * 4);
    float* H4    = (float*)carve((size_t)NN * 128 * 4);
    float* Yn    = (float*)carve((size_t)TSZ * 256 * 4);
    // make sure the always-live tail starts beyond Bmat's alias span
    size_t bspan = ((size_t)TSZ * DSZ * 4 + 255) & ~(size_t)255;
    if (off < bspan) off = bspan;
    float* rbuf     = (float*)carve(TSZ * 4);
    float* md0      = (float*)carve(256);
    unsigned* minb  = (unsigned*)carve(256);
    float* dbD      = (float*)carve(DSZ * 4);
    float* dbT      = (float*)carve(TSZ * 4);
    float* drug_k   = (float*)carve((size_t)DSZ * DSZ * 4);
    float* tgt_k    = (float*)carve((size_t)TSZ * TSZ * 4);

    // ---- CSR build ----
    hipMemsetAsync(cnt, 0, (NN + 1) * 4, stream);
    hist_kernel<<<(NE_TOT + 255) / 256, 256, 0, stream>>>(ei, cnt);
    scan_kernel<<<1, 1024, 0, stream>>>(cnt, row_ofs);
    copy_cursor<<<(NN + 255) / 256, 256, 0, stream>>>(row_ofs, cursor);
    scatter_kernel<<<(NE_TOT + 255) / 256, 256, 0, stream>>>(ei, cursor, col);

    // ---- layer 1 (K=6144, split-K=8 for occupancy) ----
    hipMemsetAsync(z, 0, (size_t)NN * 256 * 4, stream);
    gemm64<true><<<dim3(256 / 64, NN / 64, 8), 256, 0, stream>>>(x, W1, z, NN, 256, NN);
    attn_scores<<<NN, 256, 0, stream>>>(z, as1, ad1, s_src, s_dst, 256, 64);
    gat_aggregate<256, 64><<<NN / 4, 256, 0, stream>>>(z, row_ofs, col, s_src, s_dst, b1, H1);

    // ---- layers 2-4 ----
    gemm64<false><<<dim3(256 / 64, NN / 64), 256, 0, stream>>>(H1, W2, z, NN, 256, 256);
    attn_scores<<<NN, 256, 0, stream>>>(z, as2, ad2, s_src, s_dst, 256, 64);
    gat_aggregate<256, 64><<<NN / 4, 256, 0, stream>>>(z, row_ofs, col, s_src, s_dst, b2, H2);

    gemm64<false><<<dim3(256 / 64, NN / 64), 256, 0, stream>>>(H2, W3, z, NN, 256, 256);
    attn_scores<<<NN, 256, 0, stream>>>(z, as3, ad3, s_src, s_dst, 256, 64);
    gat_aggregate<256, 64><<<NN / 4, 256, 0, stream>>>(z, row_ofs, col, s_src, s_dst, b3, H3);

    gemm64<false><<<dim3(128 / 64, NN / 64), 256, 0, stream>>>(H3, W4, z, NN, 128, 256);
    attn_scores<<<NN, 256, 0, stream>>>(z, as4, ad4, s_src, s_dst, 128, 32);
    gat_aggregate<128, 32><<<NN / 4, 256, 0, stream>>>(z, row_ofs, col, s_src, s_dst, b4, H4);

    // ---- kernel matrices: init with 0.2*sim, then += p*gip(H_l) ----
    scale_copy<<<4096, 256, 0, stream>>>(dsim, drug_k, 0.2f, (size_t)DSZ * DSZ);
    scale_copy<<<8192, 256, 0, stream>>>(tsim, tgt_k, 0.2f, (size_t)TSZ * TSZ);

    const float PSv[4] = {1.0f, 0.5f, 0.333f, 0.25f};
    const float* Hs[4] = {H1, H2, H3, H4};
    const int Fo[4] = {256, 256, 256, 128};
    for (int l = 0; l < 4; l++) {
        // drug rows [0, DSZ)
        gip_norm<<<DSZ, Fo[l], 0, stream>>>(Hs[l], Yn, rbuf, Fo[l]);
        mean_reduce<<<1, 1024, 0, stream>>>(rbuf, md0, DSZ);
        gram64<<<dim3(DSZ / 64, DSZ / 64), 256, 0, stream>>>(Yn, drug_k, rbuf, md0,
                                                             PSv[l], DSZ, Fo[l]);
        // target rows [DSZ, NN)
        gip_norm<<<TSZ, Fo[l], 0, stream>>>(Hs[l] + (size_t)DSZ * Fo[l], Yn, rbuf, Fo[l]);
        mean_reduce<<<1, 1024, 0, stream>>>(rbuf, md0, TSZ);
        gram64<<<dim3(TSZ / 64, TSZ / 64), 256, 0, stream>>>(Yn, tgt_k, rbuf, md0,
                                                             PSv[l], TSZ, Fo[l]);
    }

    // ---- normalized_kernel ----
    init_min<<<1, 64, 0, stream>>>(minb);
    min_nonzero<<<1024, 256, 0, stream>>>(drug_k, minb + 0, (size_t)DSZ * DSZ);
    diag_abs<<<(DSZ + 255) / 256, 256, 0, stream>>>(drug_k, dbD, DSZ);
    normdiv<<<dim3(DSZ / 256, DSZ), 256, 0, stream>>>(drug_k, dbD, minb + 0, DSZ);
    min_nonzero<<<1024, 256, 0, stream>>>(tgt_k, minb + 1, (size_t)TSZ * TSZ);
    diag_abs<<<(TSZ + 255) / 256, 256, 0, stream>>>(tgt_k, dbT, TSZ);
    normdiv<<<dim3(TSZ / 256, TSZ), 256, 0, stream>>>(tgt_k, dbT, minb + 1, TSZ);

    // ---- final: out = 0.5*(drug_k@alpha1 + (tgt_k@alpha2)^T) ----
    gemm64<false><<<dim3(TSZ / 64, DSZ / 64), 256, 0, stream>>>(drug_k, alpha1, out,
                                                                DSZ, TSZ, DSZ);
    gemm64<false><<<dim3(DSZ / 64, TSZ / 64), 256, 0, stream>>>(tgt_k, alpha2, Bmat,
                                                                TSZ, DSZ, TSZ);
    combine<<<dim3(TSZ / 32, DSZ / 32), 256, 0, stream>>>(out, Bmat);
}

// Round 3
// 2310.570 us; speedup vs baseline: 1.5135x; 1.5135x over previous
//
#include <hip/hip_runtime.h>
#include <math.h>

#define NN 6144
#define DSZ 2048
#define TSZ 4096
#define NE 1048576
#define NE_TOT (NE + NN)
#define NEG_SLOPE 0.2f
#define GGAMMA 0.03125f

typedef float floatx4 __attribute__((ext_vector_type(4)));
typedef __bf16 bf16x8 __attribute__((ext_vector_type(8)));

// ---------------- CSR build (counting sort by dst) ----------------
__global__ void hist_kernel(const int* __restrict__ ei, int* __restrict__ cnt) {
    int e = blockIdx.x * blockDim.x + threadIdx.x;
    if (e >= NE_TOT) return;
    int d = (e < NE) ? ei[NE + e] : (e - NE);
    atomicAdd(&cnt[d], 1);
}

__global__ void scan_kernel(const int* __restrict__ cnt, int* __restrict__ row_ofs) {
    __shared__ int part[1024];
    int t = threadIdx.x;
    int local[6];
    int s = 0;
#pragma unroll
    for (int i = 0; i < 6; i++) { local[i] = s; s += cnt[t * 6 + i]; }
    part[t] = s;
    __syncthreads();
    for (int off = 1; off < 1024; off <<= 1) {
        int v = (t >= off) ? part[t - off] : 0;
        __syncthreads();
        part[t] += v;
        __syncthreads();
    }
    int base = (t == 0) ? 0 : part[t - 1];
#pragma unroll
    for (int i = 0; i < 6; i++) row_ofs[t * 6 + i] = base + local[i];
    if (t == 1023) row_ofs[NN] = part[1023];
}

__global__ void copy_cursor(const int* __restrict__ row_ofs, int* __restrict__ cursor) {
    int i = blockIdx.x * blockDim.x + threadIdx.x;
    if (i < NN) cursor[i] = row_ofs[i];
}

__global__ void scatter_kernel(const int* __restrict__ ei, int* __restrict__ cursor,
                               int* __restrict__ col) {
    int e = blockIdx.x * blockDim.x + threadIdx.x;
    if (e >= NE_TOT) return;
    int s, d;
    if (e < NE) { s = ei[e]; d = ei[NE + e]; } else { s = e - NE; d = s; }
    int pos = atomicAdd(&cursor[d], 1);
    col[pos] = s;
}

// ---------------- generic fp32 GEMM (layers 2-4 + fallback) ----------------
template <bool ATOMIC>
__global__ __launch_bounds__(256) void gemm64(const float* __restrict__ A,
                                              const float* __restrict__ B,
                                              float* __restrict__ C,
                                              int M, int N, int K) {
    __shared__ float As[16][68];
    __shared__ float Bs[16][68];
    const int tid = threadIdx.x;
    const int tn = tid & 15, tm = tid >> 4;
    const int bm = blockIdx.y * 64, bn = blockIdx.x * 64;
    const int ar = tid >> 2, ac = (tid & 3) * 4;
    const int br = tid >> 4, bc = (tid & 15) * 4;
    int kbeg = 0, kend = K;
    if constexpr (ATOMIC) {
        int klen = K / gridDim.z;
        kbeg = blockIdx.z * klen;
        kend = kbeg + klen;
    }
    const float* Ap = A + (size_t)(bm + ar) * K + ac;
    const float* Bp = B + (size_t)br * N + bn + bc;
    float acc[4][4] = {};
    for (int k0 = kbeg; k0 < kend; k0 += 16) {
        float4 av = *(const float4*)(Ap + k0);
        float4 bv = *(const float4*)(Bp + (size_t)k0 * N);
        As[ac + 0][ar] = av.x; As[ac + 1][ar] = av.y;
        As[ac + 2][ar] = av.z; As[ac + 3][ar] = av.w;
        *(float4*)&Bs[br][bc] = bv;
        __syncthreads();
#pragma unroll
        for (int k = 0; k < 16; k++) {
            float4 a4 = *(const float4*)&As[k][tm * 4];
            float4 b4 = *(const float4*)&Bs[k][tn * 4];
            float aa[4] = {a4.x, a4.y, a4.z, a4.w};
            float bb[4] = {b4.x, b4.y, b4.z, b4.w};
#pragma unroll
            for (int i = 0; i < 4; i++)
#pragma unroll
                for (int j = 0; j < 4; j++) acc[i][j] = fmaf(aa[i], bb[j], acc[i][j]);
        }
        __syncthreads();
    }
#pragma unroll
    for (int i = 0; i < 4; i++) {
        float* cp = C + (size_t)(bm + tm * 4 + i) * N + bn + tn * 4;
        if constexpr (ATOMIC) {
#pragma unroll
            for (int j = 0; j < 4; j++) atomicAdd(cp + j, acc[i][j]);
        } else {
            *(float4*)cp = make_float4(acc[i][0], acc[i][1], acc[i][2], acc[i][3]);
        }
    }
}

// ---------------- bf16 hi/lo split helpers ----------------
__device__ __forceinline__ ushort bf16_rne(float x) {
    unsigned u = __float_as_uint(x);
    unsigned r = (u + 0x7fffu + ((u >> 16) & 1u)) >> 16;
    return (ushort)r;
}

// elementwise split: fp32 [n] -> hi/lo bf16 [n]
__global__ void split_rm(const float* __restrict__ in, ushort* __restrict__ hi,
                         ushort* __restrict__ lo, size_t n4) {
    for (size_t i = (size_t)blockIdx.x * blockDim.x + threadIdx.x; i < n4;
         i += (size_t)gridDim.x * blockDim.x) {
        float4 v = ((const float4*)in)[i];
        float vv[4] = {v.x, v.y, v.z, v.w};
        ushort h[4], l[4];
#pragma unroll
        for (int j = 0; j < 4; j++) {
            h[j] = bf16_rne(vv[j]);
            float hf = __uint_as_float((unsigned)h[j] << 16);
            l[j] = bf16_rne(vv[j] - hf);
        }
        ((ushort4*)hi)[i] = make_ushort4(h[0], h[1], h[2], h[3]);
        ((ushort4*)lo)[i] = make_ushort4(l[0], l[1], l[2], l[3]);
    }
}

// transpose + split: fp32 [R][C] -> hiT/loT bf16 [C][R]
__global__ void split_T(const float* __restrict__ in, ushort* __restrict__ hiT,
                        ushort* __restrict__ loT, int R, int C) {
    __shared__ float tile[32][33];
    int bx = blockIdx.x * 32, by = blockIdx.y * 32;
    int tx = threadIdx.x & 31, ty = threadIdx.x >> 5;  // 32x8
#pragma unroll
    for (int k = 0; k < 32; k += 8)
        tile[ty + k][tx] = in[(size_t)(by + ty + k) * C + bx + tx];
    __syncthreads();
#pragma unroll
    for (int k = 0; k < 32; k += 8) {
        float v = tile[tx][ty + k];
        ushort h = bf16_rne(v);
        float hf = __uint_as_float((unsigned)h << 16);
        ushort l = bf16_rne(v - hf);
        size_t o = (size_t)(bx + ty + k) * R + by + tx;
        hiT[o] = h;
        loT[o] = l;
    }
}

// ---------------- bf16x3 MFMA GEMM: C[M][N] = A[M][K] @ B[N][K]^T ----------------
// A,B as hi/lo bf16 pairs. 128x128 tile, BK=32, 4 waves, 16x16x32 MFMA, x3 products.
// EPI=0: C = result. EPI=1: C += p*exp(-(r_i+r_j-2*G)*GGAMMA/md0).
// LDS swizzle: 16B slot s of row r stored at slot s ^ ((r>>1)&3)  (both-sides, rule 21;
// (r>>1)&3 makes (4r+slot) mod 8 bijective over 8 rows -> <=2-way bank aliasing, free).
__device__ __forceinline__ void gl_lds16(const void* g, void* l) {
    __builtin_amdgcn_global_load_lds(
        (const __attribute__((address_space(1))) unsigned int*)g,
        (__attribute__((address_space(3))) unsigned int*)l, 16, 0, 0);
}

template <int EPI>
__global__ __launch_bounds__(256) void gemm_bt_x3(
    const ushort* __restrict__ Ah, const ushort* __restrict__ Al,
    const ushort* __restrict__ Bh, const ushort* __restrict__ Bl,
    float* __restrict__ C, int M, int N, int K,
    const float* __restrict__ rbuf, const float* __restrict__ md0buf, float p) {
    __shared__ ushort lds[4][4096];  // Ah,Al,Bh,Bl tiles: 128 rows x 32 bf16 (64 B/row)
    const int t = threadIdx.x;
    const int bm = blockIdx.y * 128, bn = blockIdx.x * 128;

    // staging: LDS byte o = i*4096 + t*16 -> row = i*64 + (t>>2), slot = t&3
    const int srow = t >> 2;
    const int scb = (t & 3) << 4;
    const int gcb = scb ^ (((srow >> 1) & 3) << 4);  // inverse swizzle on global source
    const int wid = t >> 6, lane = t & 63;

    const ushort* srcs[4] = {Ah, Al, Bh, Bl};
    const char* g[8];
    ushort* lp[8];
#pragma unroll
    for (int b = 0; b < 4; b++) {
        int rb = (b < 2) ? bm : bn;
#pragma unroll
        for (int i = 0; i < 2; i++) {
            g[b * 2 + i] = (const char*)srcs[b] + ((size_t)(rb + i * 64 + srow) * K) * 2 + gcb;
            lp[b * 2 + i] = &lds[b][i * 2048 + wid * 512];  // wave-uniform; HW adds lane*16B
        }
    }

    floatx4 acc[4][4];
#pragma unroll
    for (int m = 0; m < 4; m++)
#pragma unroll
        for (int n = 0; n < 4; n++) acc[m][n] = (floatx4){0.f, 0.f, 0.f, 0.f};

    const int wr = (wid >> 1) << 6, wc = (wid & 1) << 6;
    const int fr = lane & 15, kh = lane >> 4;
    const int cbf = (((kh << 4) ^ (((fr >> 1) & 3) << 4)) >> 1);  // ushort ofs of frag slice

    for (int k0 = 0; k0 < K; k0 += 32) {
#pragma unroll
        for (int q = 0; q < 8; q++) gl_lds16(g[q] + (size_t)k0 * 2, lp[q]);
        __syncthreads();
        bf16x8 bhf[4], blf[4];
#pragma unroll
        for (int n = 0; n < 4; n++) {
            int r = wc + n * 16 + fr;
            bhf[n] = *(const bf16x8*)&lds[2][r * 32 + cbf];
            blf[n] = *(const bf16x8*)&lds[3][r * 32 + cbf];
        }
#pragma unroll
        for (int m = 0; m < 4; m++) {
            int r = wr + m * 16 + fr;
            bf16x8 ahf = *(const bf16x8*)&lds[0][r * 32 + cbf];
            bf16x8 alf = *(const bf16x8*)&lds[1][r * 32 + cbf];
#pragma unroll
            for (int n = 0; n < 4; n++) {
                acc[m][n] = __builtin_amdgcn_mfma_f32_16x16x32_bf16(ahf, bhf[n], acc[m][n], 0, 0, 0);
                acc[m][n] = __builtin_amdgcn_mfma_f32_16x16x32_bf16(ahf, blf[n], acc[m][n], 0, 0, 0);
                acc[m][n] = __builtin_amdgcn_mfma_f32_16x16x32_bf16(alf, bhf[n], acc[m][n], 0, 0, 0);
            }
        }
        __syncthreads();
    }

    float sc = 0.f;
    if constexpr (EPI == 1) sc = GGAMMA / md0buf[0];
#pragma unroll
    for (int m = 0; m < 4; m++) {
#pragma unroll
        for (int n = 0; n < 4; n++) {
#pragma unroll
            for (int r = 0; r < 4; r++) {
                int gr = bm + wr + m * 16 + kh * 4 + r;  // C/D: row=(lane>>4)*4+reg
                int gc = bn + wc + n * 16 + fr;          //      col=lane&15
                size_t idx = (size_t)gr * N + gc;
                if constexpr (EPI == 0) {
                    C[idx] = acc[m][n][r];
                } else {
                    float val = p * expf(-(rbuf[gr] + rbuf[gc] - 2.f * acc[m][n][r]) * sc);
                    C[idx] += val;
                }
            }
        }
    }
}

// ---------------- per-node attention scalars ----------------
__global__ void attn_scores(const float* __restrict__ z, const float* __restrict__ a_src,
                            const float* __restrict__ a_dst, float* __restrict__ s_src,
                            float* __restrict__ s_dst, int Fout, int F) {
    int n = blockIdx.x, t = threadIdx.x;
    __shared__ float r1[256], r2[256];
    float v = (t < Fout) ? z[(size_t)n * Fout + t] : 0.f;
    r1[t] = (t < Fout) ? v * a_src[t] : 0.f;
    r2[t] = (t < Fout) ? v * a_dst[t] : 0.f;
    __syncthreads();
    for (int off = F >> 1; off > 0; off >>= 1) {
        if ((t & (F - 1)) < off) { r1[t] += r1[t + off]; r2[t] += r2[t + off]; }
        __syncthreads();
    }
    if (t < Fout && (t & (F - 1)) == 0) {
        int h = t / F;
        s_src[n * 4 + h] = r1[t];
        s_dst[n * 4 + h] = r2[t];
    }
}

// ---------------- GAT aggregate ----------------
template <int FOUT, int F>
__global__ __launch_bounds__(256) void gat_aggregate(
    const float* __restrict__ z, const int* __restrict__ row_ofs,
    const int* __restrict__ col, const float* __restrict__ s_src,
    const float* __restrict__ s_dst, const float* __restrict__ bias,
    float* __restrict__ H) {
    constexpr int VPL = FOUT / 64;
    int wave = threadIdx.x >> 6, lane = threadIdx.x & 63;
    int n = blockIdx.x * 4 + wave;
    int beg = row_ofs[n], end = row_ofs[n + 1];
    int f0 = lane * VPL;
    int h = f0 / F;
    float4 sd4 = *(const float4*)&s_dst[n * 4];
    float mx[4] = {-__builtin_inff(), -__builtin_inff(), -__builtin_inff(), -__builtin_inff()};
    for (int e = beg + lane; e < end; e += 64) {
        int s = col[e];
        float4 ss = *(const float4*)&s_src[s * 4];
        float l0 = ss.x + sd4.x; l0 = l0 > 0.f ? l0 : NEG_SLOPE * l0;
        float l1 = ss.y + sd4.y; l1 = l1 > 0.f ? l1 : NEG_SLOPE * l1;
        float l2 = ss.z + sd4.z; l2 = l2 > 0.f ? l2 : NEG_SLOPE * l2;
        float l3 = ss.w + sd4.w; l3 = l3 > 0.f ? l3 : NEG_SLOPE * l3;
        mx[0] = fmaxf(mx[0], l0); mx[1] = fmaxf(mx[1], l1);
        mx[2] = fmaxf(mx[2], l2); mx[3] = fmaxf(mx[3], l3);
    }
#pragma unroll
    for (int off = 32; off > 0; off >>= 1) {
#pragma unroll
        for (int hh = 0; hh < 4; hh++) mx[hh] = fmaxf(mx[hh], __shfl_xor(mx[hh], off));
    }
    float mh = (h == 0) ? mx[0] : (h == 1) ? mx[1] : (h == 2) ? mx[2] : mx[3];
    float sdh = (h == 0) ? sd4.x : (h == 1) ? sd4.y : (h == 2) ? sd4.z : sd4.w;
    float acc[VPL] = {};
    float wsum = 0.f;
    for (int e = beg; e < end; e++) {
        int s = col[e];
        float l = s_src[s * 4 + h] + sdh;
        l = l > 0.f ? l : NEG_SLOPE * l;
        float w = expf(l - mh);
        wsum += w;
        const float* zp = z + (size_t)s * FOUT + f0;
        if constexpr (VPL == 4) {
            float4 zv = *(const float4*)zp;
            acc[0] = fmaf(w, zv.x, acc[0]); acc[1] = fmaf(w, zv.y, acc[1]);
            acc[2] = fmaf(w, zv.z, acc[2]); acc[3] = fmaf(w, zv.w, acc[3]);
        } else {
            float2 zv = *(const float2*)zp;
            acc[0] = fmaf(w, zv.x, acc[0]); acc[1] = fmaf(w, zv.y, acc[1]);
        }
    }
    float inv = 1.f / wsum;
#pragma unroll
    for (int i = 0; i < VPL; i++) {
        float o = acc[i] * inv + bias[f0 + i];
        H[(size_t)n * FOUT + f0 + i] = o > 0.f ? o : 0.f;
    }
}

// ---------------- GIP row normalize + sq-norm ----------------
__global__ void gip_norm(const float* __restrict__ Y, float* __restrict__ Yn,
                         float* __restrict__ r, int Fout) {
    int row = blockIdx.x, t = threadIdx.x;
    __shared__ float s1[256], s2[256];
    float v = Y[(size_t)row * Fout + t];
    s1[t] = v; s2[t] = v;
    __syncthreads();
    for (int off = blockDim.x >> 1; off > 0; off >>= 1) {
        if (t < off) {
            s1[t] = fminf(s1[t], s1[t + off]);
            s2[t] = fmaxf(s2[t], s2[t + off]);
        }
        __syncthreads();
    }
    float mn = s1[0], mx = s2[0];
    float rng = mx - mn;
    if (rng == 0.f) rng = 1.f;
    float yn = (v - mn) / rng;
    Yn[(size_t)row * Fout + t] = yn;
    __syncthreads();
    s1[t] = yn * yn;
    __syncthreads();
    for (int off = blockDim.x >> 1; off > 0; off >>= 1) {
        if (t < off) s1[t] += s1[t + off];
        __syncthreads();
    }
    if (t == 0) r[row] = s1[0];
}

__global__ void mean_reduce(const float* __restrict__ r, float* __restrict__ md0, int M) {
    __shared__ float s[1024];
    int t = threadIdx.x;
    float acc = 0.f;
    for (int i = t; i < M; i += 1024) acc += r[i];
    s[t] = acc;
    __syncthreads();
    for (int off = 512; off > 0; off >>= 1) {
        if (t < off) s[t] += s[t + off];
        __syncthreads();
    }
    if (t == 0) md0[0] = s[0] / (float)M;
}

// ---------------- fp32 gram (fallback path only) ----------------
__global__ __launch_bounds__(256) void gram64(const float* __restrict__ Y,
                                              float* __restrict__ Kacc,
                                              const float* __restrict__ rbuf,
                                              const float* __restrict__ md0buf,
                                              float p, int M, int K) {
    __shared__ float As[16][68];
    __shared__ float Bs[16][68];
    const int tid = threadIdx.x;
    const int tn = tid & 15, tm = tid >> 4;
    const int bm = blockIdx.y * 64, bn = blockIdx.x * 64;
    const int ar = tid >> 2, ac = (tid & 3) * 4;
    const float* Ap = Y + (size_t)(bm + ar) * K + ac;
    const float* Bp = Y + (size_t)(bn + ar) * K + ac;
    float acc[4][4] = {};
    for (int k0 = 0; k0 < K; k0 += 16) {
        float4 av = *(const float4*)(Ap + k0);
        float4 bv = *(const float4*)(Bp + k0);
        As[ac + 0][ar] = av.x; As[ac + 1][ar] = av.y;
        As[ac + 2][ar] = av.z; As[ac + 3][ar] = av.w;
        Bs[ac + 0][ar] = bv.x; Bs[ac + 1][ar] = bv.y;
        Bs[ac + 2][ar] = bv.z; Bs[ac + 3][ar] = bv.w;
        __syncthreads();
#pragma unroll
        for (int k = 0; k < 16; k++) {
            float4 a4 = *(const float4*)&As[k][tm * 4];
            float4 b4 = *(const float4*)&Bs[k][tn * 4];
            float aa[4] = {a4.x, a4.y, a4.z, a4.w};
            float bb[4] = {b4.x, b4.y, b4.z, b4.w};
#pragma unroll
            for (int i = 0; i < 4; i++)
#pragma unroll
                for (int j = 0; j < 4; j++) acc[i][j] = fmaf(aa[i], bb[j], acc[i][j]);
        }
        __syncthreads();
    }
    float sc = GGAMMA / md0buf[0];
    float ri[4], rj[4];
#pragma unroll
    for (int i = 0; i < 4; i++) ri[i] = rbuf[bm + tm * 4 + i];
#pragma unroll
    for (int j = 0; j < 4; j++) rj[j] = rbuf[bn + tn * 4 + j];
#pragma unroll
    for (int i = 0; i < 4; i++) {
#pragma unroll
        for (int j = 0; j < 4; j++) {
            float val = p * expf(-(ri[i] + rj[j] - 2.f * acc[i][j]) * sc);
            size_t idx = (size_t)(bm + tm * 4 + i) * M + bn + tn * 4 + j;
            Kacc[idx] += val;
        }
    }
}

// ---------------- misc elementwise ----------------
__global__ void scale_copy(const float* __restrict__ src, float* __restrict__ dst,
                           float p, size_t n) {
    for (size_t i = (size_t)blockIdx.x * blockDim.x + threadIdx.x; i < n;
         i += (size_t)gridDim.x * blockDim.x)
        dst[i] = p * src[i];
}

__global__ void init_min(unsigned* minb) {
    if (threadIdx.x == 0 && blockIdx.x == 0) { minb[0] = 0x7f800000u; minb[1] = 0x7f800000u; }
}

__global__ void min_nonzero(const float* __restrict__ Km, unsigned* __restrict__ minb,
                            size_t total) {
    unsigned lm = 0x7f800000u;
    for (size_t i = (size_t)blockIdx.x * blockDim.x + threadIdx.x; i < total;
         i += (size_t)gridDim.x * blockDim.x) {
        float v = fabsf(Km[i]);
        if (v != 0.f) lm = min(lm, __float_as_uint(v));
    }
#pragma unroll
    for (int off = 32; off > 0; off >>= 1)
        lm = min(lm, (unsigned)__shfl_xor((int)lm, off));
    if ((threadIdx.x & 63) == 0) atomicMin(minb, lm);
}

__global__ void diag_abs(const float* __restrict__ Km, float* __restrict__ dbuf, int M) {
    int i = blockIdx.x * blockDim.x + threadIdx.x;
    if (i < M) dbuf[i] = fabsf(Km[(size_t)i * M + i]);
}

__global__ void normdiv(float* __restrict__ Km, const float* __restrict__ dbuf,
                        const unsigned* __restrict__ minb, int M) {
    int colc = blockIdx.x * blockDim.x + threadIdx.x;
    int row = blockIdx.y;
    float minv = __uint_as_float(minb[0]);
    float v = fabsf(Km[(size_t)row * M + colc]);
    if (v == 0.f) v = minv;
    float dj = dbuf[colc];
    if (dj == 0.f) dj = minv;
    Km[(size_t)row * M + colc] = v / dj;
}

__global__ void combine(float* __restrict__ out, const float* __restrict__ Bm) {
    __shared__ float t[32][33];
    int bx = blockIdx.x * 32;
    int by = blockIdx.y * 32;
    int tx = threadIdx.x & 31, ty = threadIdx.x >> 5;
#pragma unroll
    for (int k = 0; k < 32; k += 8)
        t[ty + k][tx] = Bm[(size_t)(bx + ty + k) * DSZ + by + tx];
    __syncthreads();
#pragma unroll
    for (int k = 0; k < 32; k += 8) {
        size_t idx = (size_t)(by + ty + k) * TSZ + bx + tx;
        out[idx] = 0.5f * (out[idx] + t[tx][ty + k]);
    }
}

// ============================================================================
extern "C" void kernel_launch(void* const* d_in, const int* in_sizes, int n_in,
                              void* d_out, int out_size, void* d_ws, size_t ws_size,
                              hipStream_t stream) {
    (void)in_sizes; (void)n_in; (void)out_size;
    const float* x      = (const float*)d_in[0];
    const int*   ei     = (const int*)d_in[1];
    const float* W1     = (const float*)d_in[2];
    const float* as1    = (const float*)d_in[3];
    const float* ad1    = (const float*)d_in[4];
    const float* b1     = (const float*)d_in[5];
    const float* W2     = (const float*)d_in[6];
    const float* as2    = (const float*)d_in[7];
    const float* ad2    = (const float*)d_in[8];
    const float* b2     = (const float*)d_in[9];
    const float* W3     = (const float*)d_in[10];
    const float* as3    = (const float*)d_in[11];
    const float* ad3    = (const float*)d_in[12];
    const float* b3     = (const float*)d_in[13];
    const float* W4     = (const float*)d_in[14];
    const float* as4    = (const float*)d_in[15];
    const float* ad4    = (const float*)d_in[16];
    const float* b4     = (const float*)d_in[17];
    const float* alpha1 = (const float*)d_in[18];
    const float* alpha2 = (const float*)d_in[19];
    const float* dsim   = (const float*)d_in[20];
    const float* tsim   = (const float*)d_in[21];
    float* out = (float*)d_out;

    // ---- workspace carve ----
    char* base = (char*)d_ws;
    size_t off = 0;
    auto carve = [&](size_t bytes) -> void* {
        void* p = base + off;
        off = (off + bytes + 255) & ~(size_t)255;
        return p;
    };
    float* Bmat  = (float*)base;  // aliases front region (dead by final phase)
    int* col     = (int*)carve((size_t)NE_TOT * 4);
    int* cnt     = (int*)carve((NN + 1) * 4);
    int* row_ofs = (int*)carve((NN + 1) * 4);
    int* cursor  = (int*)carve(NN * 4);
    float* s_src = (float*)carve((size_t)NN * 4 * 4);
    float* s_dst = (float*)carve((size_t)NN * 4 * 4);
    float* z     = (float*)carve((size_t)NN * 256 * 4);
    float* H1    = (float*)carve((size_t)NN * 256 * 4);
    float* H2    = (float*)carve((size_t)NN * 256 * 4);
    float* H3    = (float*)carve((size_t)NN * 256 * 4);
    float* H4    = (float*)carve((size_t)NN * 128 * 4);
    float* Yn    = (float*)carve((size_t)TSZ * 256 * 4);
    size_t bspan = ((size_t)TSZ * DSZ * 4 + 255) & ~(size_t)255;
    if (off < bspan) off = bspan;  // keep always-live tail clear of Bmat alias
    float* rbuf     = (float*)carve(TSZ * 4);
    float* md0      = (float*)carve(256);
    unsigned* minb  = (unsigned*)carve(256);
    float* dbD      = (float*)carve(DSZ * 4);
    float* dbT      = (float*)carve(TSZ * 4);
    float* drug_k   = (float*)carve((size_t)DSZ * DSZ * 4);
    float* tgt_k    = (float*)carve((size_t)TSZ * TSZ * 4);
    // bf16x3 split buffers
    ushort* Ynh  = (ushort*)carve((size_t)TSZ * 256 * 2);
    ushort* Ynl  = (ushort*)carve((size_t)TSZ * 256 * 2);
    ushort* dkh  = (ushort*)carve((size_t)DSZ * DSZ * 2);
    ushort* dkl  = (ushort*)carve((size_t)DSZ * DSZ * 2);
    ushort* tkh  = (ushort*)carve((size_t)TSZ * TSZ * 2);
    ushort* tkl  = (ushort*)carve((size_t)TSZ * TSZ * 2);
    ushort* a1Th = (ushort*)carve((size_t)TSZ * DSZ * 2);
    ushort* a1Tl = (ushort*)carve((size_t)TSZ * DSZ * 2);
    ushort* a2Th = (ushort*)carve((size_t)DSZ * TSZ * 2);
    ushort* a2Tl = (ushort*)carve((size_t)DSZ * TSZ * 2);
    const bool use_mfma = (off <= ws_size);  // ws_size is call-invariant: graph-safe
    // layer-1 split (x is big: +151 MB) — separate guard
    ushort* xh   = (ushort*)carve((size_t)NN * NN * 2);
    ushort* xl   = (ushort*)carve((size_t)NN * NN * 2);
    ushort* w1Th = (ushort*)carve((size_t)NN * 256 * 2);
    ushort* w1Tl = (ushort*)carve((size_t)NN * 256 * 2);
    const bool use_mfma_l1 = use_mfma && (off <= ws_size);

    // ---- CSR build ----
    hipMemsetAsync(cnt, 0, (NN + 1) * 4, stream);
    hist_kernel<<<(NE_TOT + 255) / 256, 256, 0, stream>>>(ei, cnt);
    scan_kernel<<<1, 1024, 0, stream>>>(cnt, row_ofs);
    copy_cursor<<<(NN + 255) / 256, 256, 0, stream>>>(row_ofs, cursor);
    scatter_kernel<<<(NE_TOT + 255) / 256, 256, 0, stream>>>(ei, cursor, col);

    // ---- layer 1 ----
    if (use_mfma_l1) {
        split_rm<<<4096, 256, 0, stream>>>(x, xh, xl, (size_t)NN * NN / 4);
        split_T<<<dim3(256 / 32, NN / 32), 256, 0, stream>>>(W1, w1Th, w1Tl, NN, 256);
        gemm_bt_x3<0><<<dim3(256 / 128, NN / 128), 256, 0, stream>>>(
            xh, xl, w1Th, w1Tl, z, NN, 256, NN, rbuf, md0, 0.f);
    } else {
        hipMemsetAsync(z, 0, (size_t)NN * 256 * 4, stream);
        gemm64<true><<<dim3(256 / 64, NN / 64, 8), 256, 0, stream>>>(x, W1, z, NN, 256, NN);
    }
    attn_scores<<<NN, 256, 0, stream>>>(z, as1, ad1, s_src, s_dst, 256, 64);
    gat_aggregate<256, 64><<<NN / 4, 256, 0, stream>>>(z, row_ofs, col, s_src, s_dst, b1, H1);

    // ---- layers 2-4 (small K: fp32 SIMT fine) ----
    gemm64<false><<<dim3(256 / 64, NN / 64), 256, 0, stream>>>(H1, W2, z, NN, 256, 256);
    attn_scores<<<NN, 256, 0, stream>>>(z, as2, ad2, s_src, s_dst, 256, 64);
    gat_aggregate<256, 64><<<NN / 4, 256, 0, stream>>>(z, row_ofs, col, s_src, s_dst, b2, H2);

    gemm64<false><<<dim3(256 / 64, NN / 64), 256, 0, stream>>>(H2, W3, z, NN, 256, 256);
    attn_scores<<<NN, 256, 0, stream>>>(z, as3, ad3, s_src, s_dst, 256, 64);
    gat_aggregate<256, 64><<<NN / 4, 256, 0, stream>>>(z, row_ofs, col, s_src, s_dst, b3, H3);

    gemm64<false><<<dim3(128 / 64, NN / 64), 256, 0, stream>>>(H3, W4, z, NN, 128, 256);
    attn_scores<<<NN, 256, 0, stream>>>(z, as4, ad4, s_src, s_dst, 128, 32);
    gat_aggregate<128, 32><<<NN / 4, 256, 0, stream>>>(z, row_ofs, col, s_src, s_dst, b4, H4);

    // ---- kernel matrices ----
    scale_copy<<<4096, 256, 0, stream>>>(dsim, drug_k, 0.2f, (size_t)DSZ * DSZ);
    scale_copy<<<8192, 256, 0, stream>>>(tsim, tgt_k, 0.2f, (size_t)TSZ * TSZ);

    const float PSv[4] = {1.0f, 0.5f, 0.333f, 0.25f};
    const float* Hs[4] = {H1, H2, H3, H4};
    const int Fo[4] = {256, 256, 256, 128};
    for (int l = 0; l < 4; l++) {
        gip_norm<<<DSZ, Fo[l], 0, stream>>>(Hs[l], Yn, rbuf, Fo[l]);
        mean_reduce<<<1, 1024, 0, stream>>>(rbuf, md0, DSZ);
        if (use_mfma) {
            split_rm<<<2048, 256, 0, stream>>>(Yn, Ynh, Ynl, (size_t)DSZ * Fo[l] / 4);
            gemm_bt_x3<1><<<dim3(DSZ / 128, DSZ / 128), 256, 0, stream>>>(
                Ynh, Ynl, Ynh, Ynl, drug_k, DSZ, DSZ, Fo[l], rbuf, md0, PSv[l]);
        } else {
            gram64<<<dim3(DSZ / 64, DSZ / 64), 256, 0, stream>>>(Yn, drug_k, rbuf, md0,
                                                                 PSv[l], DSZ, Fo[l]);
        }
        gip_norm<<<TSZ, Fo[l], 0, stream>>>(Hs[l] + (size_t)DSZ * Fo[l], Yn, rbuf, Fo[l]);
        mean_reduce<<<1, 1024, 0, stream>>>(rbuf, md0, TSZ);
        if (use_mfma) {
            split_rm<<<2048, 256, 0, stream>>>(Yn, Ynh, Ynl, (size_t)TSZ * Fo[l] / 4);
            gemm_bt_x3<1><<<dim3(TSZ / 128, TSZ / 128), 256, 0, stream>>>(
                Ynh, Ynl, Ynh, Ynl, tgt_k, TSZ, TSZ, Fo[l], rbuf, md0, PSv[l]);
        } else {
            gram64<<<dim3(TSZ / 64, TSZ / 64), 256, 0, stream>>>(Yn, tgt_k, rbuf, md0,
                                                                 PSv[l], TSZ, Fo[l]);
        }
    }

    // ---- normalized_kernel ----
    init_min<<<1, 64, 0, stream>>>(minb);
    min_nonzero<<<1024, 256, 0, stream>>>(drug_k, minb + 0, (size_t)DSZ * DSZ);
    diag_abs<<<(DSZ + 255) / 256, 256, 0, stream>>>(drug_k, dbD, DSZ);
    normdiv<<<dim3(DSZ / 256, DSZ), 256, 0, stream>>>(drug_k, dbD, minb + 0, DSZ);
    min_nonzero<<<1024, 256, 0, stream>>>(tgt_k, minb + 1, (size_t)TSZ * TSZ);
    diag_abs<<<(TSZ + 255) / 256, 256, 0, stream>>>(tgt_k, dbT, TSZ);
    normdiv<<<dim3(TSZ / 256, TSZ), 256, 0, stream>>>(tgt_k, dbT, minb + 1, TSZ);

    // ---- final: out = 0.5*(drug_k@alpha1 + (tgt_k@alpha2)^T) ----
    if (use_mfma) {
        split_T<<<dim3(TSZ / 32, DSZ / 32), 256, 0, stream>>>(alpha1, a1Th, a1Tl, DSZ, TSZ);
        split_T<<<dim3(DSZ / 32, TSZ / 32), 256, 0, stream>>>(alpha2, a2Th, a2Tl, TSZ, DSZ);
        split_rm<<<2048, 256, 0, stream>>>(drug_k, dkh, dkl, (size_t)DSZ * DSZ / 4);
        split_rm<<<2048, 256, 0, stream>>>(tgt_k, tkh, tkl, (size_t)TSZ * TSZ / 4);
        gemm_bt_x3<0><<<dim3(TSZ / 128, DSZ / 128), 256, 0, stream>>>(
            dkh, dkl, a1Th, a1Tl, out, DSZ, TSZ, DSZ, rbuf, md0, 0.f);
        gemm_bt_x3<0><<<dim3(DSZ / 128, TSZ / 128), 256, 0, stream>>>(
            tkh, tkl, a2Th, a2Tl, Bmat, TSZ, DSZ, TSZ, rbuf, md0, 0.f);
    } else {
        gemm64<false><<<dim3(TSZ / 64, DSZ / 64), 256, 0, stream>>>(drug_k, alpha1, out,
                                                                    DSZ, TSZ, DSZ);
        gemm64<false><<<dim3(DSZ / 64, TSZ / 64), 256, 0, stream>>>(tgt_k, alpha2, Bmat,
                                                                    TSZ, DSZ, TSZ);
    }
    combine<<<dim3(TSZ / 32, DSZ / 32), 256, 0, stream>>>(out, Bmat);
}